// Round 10
// baseline (145.450 us; speedup 1.0000x reference)
//
#include <hip/hip_runtime.h>

#define DEV __device__ __forceinline__

typedef __attribute__((ext_vector_type(8))) short bf16x8;
typedef __attribute__((ext_vector_type(4))) float f32x4;

constexpr int Nn = 4096, Dd = 256, Kk = 128;
constexpr int SEGS = 16;          // k1 segments per batch (256 rows each)
constexpr int CH2  = 8;           // k2 n-chunks per batch (512 rows each)
constexpr int NCH  = Nn / CH2;    // 512 rows per k2 block
constexpr int NSTEP = 64;         // k2 n-step

DEV unsigned short f2bf(float f) {
  unsigned int u = __builtin_bit_cast(unsigned int, f);
  u += 0x7FFFu + ((u >> 16) & 1u);          // RNE; inputs are finite
  return (unsigned short)(u >> 16);
}
DEV float bf2f(unsigned short h) {
  unsigned int u = (unsigned int)h << 16;
  return __builtin_bit_cast(float, u);
}

// k2 xT tile: row d = 128B (64 bf16 n-values). Swizzle 16B slot by
// hh(d) = (d&7)^((d>>4)&7)^(((d>>7)&1)<<1):
//  - staging writes (lane ln scatters d=ln*16+j): <=4-way (1.58x, writes only)
//  - b128 frag reads (lanes d=base+ln):           <=2-way (free)
DEV unsigned lds2(unsigned d, unsigned nbyte) {
  unsigned hh = (d & 7u) ^ ((d >> 4) & 7u) ^ (((d >> 7) & 1u) << 1);
  return d * 128u + (nbyte ^ (hh << 4));
}

__global__ void enc_prep(const float* __restrict__ cw, const float* __restrict__ sc,
                         unsigned short* __restrict__ cbf, float2* __restrict__ tab) {
  int k = blockIdx.x, l = threadIdx.x;          // 128 blocks x 64 threads
  float4 u = *(const float4*)(cw + k * Dd + l * 4);
  float s2 = u.x * u.x + u.y * u.y + u.z * u.z + u.w * u.w;
  #pragma unroll
  for (int o = 1; o < 64; o <<= 1) s2 += __shfl_xor(s2, o);
  unsigned short* dst = cbf + k * Dd + l * 4;
  dst[0] = f2bf(u.x); dst[1] = f2bf(u.y); dst[2] = f2bf(u.z); dst[3] = f2bf(u.w);
  if (l == 0) { float s = sc[k]; tab[k] = make_float2(s * s2, 2.0f * s); }
}

// ---------------- k1: W^T producer. Fully independent waves, no block sync
// after the 1KB tab stage. Each wave: 16 rows, S^T = mfma(c,x), softmax in
// registers, 32 bf16 stores of W^T[b][k][n].
__global__ __launch_bounds__(1024) void enc_w(
    const float* __restrict__ x, const unsigned short* __restrict__ cbf,
    const float2* __restrict__ tab, unsigned short* __restrict__ Wt) {
  __shared__ float2 tabL[Kk];
  const int tid = threadIdx.x;
  const int w  = tid >> 6;             // wave 0..15
  const int l  = tid & 63;
  const int g  = l >> 4;               // 16-lane group 0..3
  const int ln = l & 15;
  if (tid < Kk) tabL[tid] = tab[tid];
  __syncthreads();

  const int b   = blockIdx.x >> 4;     // 32 batches x 16 segments
  const int seg = blockIdx.x & 15;
  const int nrow = seg * 256 + w * 16 + ln;            // row within batch
  const float* xrow = x + ((size_t)b * Nn + nrow) * Dd;

  f32x4 s1[8];
  const f32x4 zero4 = {0.f, 0.f, 0.f, 0.f};
  #pragma unroll
  for (int f = 0; f < 8; ++f) s1[f] = zero4;
  float x2p = 0.f;

  #pragma unroll
  for (int ks = 0; ks < 8; ++ks) {
    const int d0 = ks * 32 + g * 8;
    float4 u0 = *(const float4*)(xrow + d0);
    float4 u1 = *(const float4*)(xrow + d0 + 4);
    x2p += u0.x*u0.x + u0.y*u0.y + u0.z*u0.z + u0.w*u0.w
         + u1.x*u1.x + u1.y*u1.y + u1.z*u1.z + u1.w*u1.w;
    bf16x8 xv;
    xv[0] = (short)f2bf(u0.x); xv[1] = (short)f2bf(u0.y);
    xv[2] = (short)f2bf(u0.z); xv[3] = (short)f2bf(u0.w);
    xv[4] = (short)f2bf(u1.x); xv[5] = (short)f2bf(u1.y);
    xv[6] = (short)f2bf(u1.z); xv[7] = (short)f2bf(u1.w);
    #pragma unroll
    for (int f = 0; f < 8; ++f) {
      bf16x8 a = *(const bf16x8*)(cbf + (f * 16 + ln) * Dd + d0);
      s1[f] = __builtin_amdgcn_mfma_f32_16x16x32_bf16(a, xv, s1[f], 0, 0, 0);
    }
  }

  x2p += __shfl_xor(x2p, 16); x2p += __shfl_xor(x2p, 32);
  const float hx2 = 0.5f * x2p;
  float ssum = 0.f;
  #pragma unroll
  for (int f = 0; f < 8; ++f) {
    #pragma unroll
    for (int r = 0; r < 4; ++r) {
      const float2 ab = tabL[f * 16 + g * 4 + r];
      const float ev = __expf(ab.x + ab.y * (hx2 - s1[f][r]));
      s1[f][r] = ev;
      ssum += ev;
    }
  }
  ssum += __shfl_xor(ssum, 16); ssum += __shfl_xor(ssum, 32);
  const float rinv = 1.0f / ssum;

  unsigned short* wb = Wt + (size_t)b * Kk * Nn + nrow;
  #pragma unroll
  for (int f = 0; f < 8; ++f) {
    #pragma unroll
    for (int r = 0; r < 4; ++r) {
      const int cwi = f * 16 + g * 4 + r;
      wb[(size_t)cwi * Nn] = f2bf(s1[f][r] * rinv);
    }
  }
}

// ---------------- k2: Ep_chunk[k][d] = sum_n W^T[k][n] x[n][d] - Wsum_chunk[k] c[k][d]
// Double-buffered LDS xT, T14 issue-early/write-late staging, W frags from L2,
// Wsum accumulated from A-fragments in-register. PM: 0 = fp32 partials, 2 = atomic.
template<int PM>
__global__ __launch_bounds__(1024) void enc_e(
    const float* __restrict__ x, const unsigned short* __restrict__ Wt,
    const float* __restrict__ cwf, float* __restrict__ Ep, float* __restrict__ out) {
  __shared__ __align__(16) char xs[2 * 32768];   // xT [256 d][64 n] bf16, dbuf
  __shared__ float wsL[Kk];

  const int tid = threadIdx.x;
  const int w  = tid >> 6;             // wave 0..15
  const int l  = tid & 63;
  const int g  = l >> 4;
  const int ln = l & 15;
  const int wr = w >> 2, wc = w & 3;   // 4x4 wave grid over E(128k x 256d)
  const int b  = blockIdx.x >> 3, ch = blockIdx.x & 7;

  const float* xb = x + ((size_t)b * Nn + ch * NCH) * Dd;
  const unsigned short* Wb = Wt + (size_t)b * Kk * Nn + ch * NCH;

  // staging role: row n_loc = w*4+g (0..63), d-slice = ln*16..+15 (16 floats)
  const int srow = w * 4 + g;
  const int sd0  = ln * 16;
  const unsigned swz0 = lds2((unsigned)(sd0 + 0), (unsigned)(srow * 2)) & 0x7fu; // per-d base varies; compute inline below

  f32x4 acc[2][4];
  const f32x4 zero4 = {0.f, 0.f, 0.f, 0.f};
  #pragma unroll
  for (int mi = 0; mi < 2; ++mi)
    #pragma unroll
    for (int ni = 0; ni < 4; ++ni) acc[mi][ni] = zero4;
  float ws0 = 0.f, ws1 = 0.f;

  // prologue: stage step 0 into buf 0
  {
    const float* p = xb + (size_t)srow * Dd + sd0;
    float4 u0 = *(const float4*)(p + 0), u1 = *(const float4*)(p + 4);
    float4 u2 = *(const float4*)(p + 8), u3 = *(const float4*)(p + 12);
    const float uu[16] = {u0.x,u0.y,u0.z,u0.w, u1.x,u1.y,u1.z,u1.w,
                          u2.x,u2.y,u2.z,u2.w, u3.x,u3.y,u3.z,u3.w};
    #pragma unroll
    for (int j = 0; j < 16; ++j)
      *(unsigned short*)(xs + lds2((unsigned)(sd0 + j), (unsigned)(srow * 2))) = f2bf(uu[j]);
  }
  __syncthreads();

  int cur = 0;
  for (int s = 0; s < CH2; ++s) {          // 8 n-steps of 64
    // T14: issue next step's global loads before compute
    float4 n0, n1, n2, n3;
    if (s + 1 < CH2) {
      const float* p = xb + (size_t)((s + 1) * NSTEP + srow) * Dd + sd0;
      n0 = *(const float4*)(p + 0); n1 = *(const float4*)(p + 4);
      n2 = *(const float4*)(p + 8); n3 = *(const float4*)(p + 12);
    }

    const char* xcur = xs + (cur << 15);
    #pragma unroll
    for (int ks2 = 0; ks2 < 2; ++ks2) {
      const int ncol = s * NSTEP + ks2 * 32 + g * 8;     // within-chunk n of this frag
      bf16x8 af[2], bg[4];
      #pragma unroll
      for (int mi = 0; mi < 2; ++mi)
        af[mi] = *(const bf16x8*)(Wb + (size_t)(wr * 32 + mi * 16 + ln) * Nn + ncol);
      #pragma unroll
      for (int ni = 0; ni < 4; ++ni)
        bg[ni] = *(const bf16x8*)(xcur + lds2((unsigned)(wc * 64 + ni * 16 + ln),
                                              (unsigned)((ks2 * 32 + g * 8) * 2)));
      #pragma unroll
      for (int mi = 0; mi < 2; ++mi) {
        float wsp = 0.f;
        #pragma unroll
        for (int j = 0; j < 8; ++j) wsp += bf2f((unsigned short)af[mi][j]);
        if (mi == 0) ws0 += wsp; else ws1 += wsp;
        #pragma unroll
        for (int ni = 0; ni < 4; ++ni)
          acc[mi][ni] = __builtin_amdgcn_mfma_f32_16x16x32_bf16(af[mi], bg[ni], acc[mi][ni], 0, 0, 0);
      }
    }
    __syncthreads();                        // everyone done reading xs[cur^1]'s successor safely
    if (s + 1 < CH2) {
      char* xn = xs + ((cur ^ 1) << 15);
      const float uu[16] = {n0.x,n0.y,n0.z,n0.w, n1.x,n1.y,n1.z,n1.w,
                            n2.x,n2.y,n2.z,n2.w, n3.x,n3.y,n3.z,n3.w};
      #pragma unroll
      for (int j = 0; j < 16; ++j)
        *(unsigned short*)(xn + lds2((unsigned)(sd0 + j), (unsigned)(srow * 2))) = f2bf(uu[j]);
    }
    __syncthreads();
    cur ^= 1;
  }

  // Wsum_chunk[k]: reduce across g (frags covered disjoint n-slices), publish once
  ws0 += __shfl_xor(ws0, 16); ws0 += __shfl_xor(ws0, 32);
  ws1 += __shfl_xor(ws1, 16); ws1 += __shfl_xor(ws1, 32);
  if (wc == 0 && l < 16) {
    wsL[wr * 32 + l]      = ws0;
    wsL[wr * 32 + 16 + l] = ws1;
  }
  __syncthreads();

  #pragma unroll
  for (int mi = 0; mi < 2; ++mi) {
    #pragma unroll
    for (int r = 0; r < 4; ++r) {
      const int k = wr * 32 + mi * 16 + g * 4 + r;
      const float wsv = wsL[k];
      #pragma unroll
      for (int ni = 0; ni < 4; ++ni) {
        const int d = wc * 64 + ni * 16 + ln;
        const float v = acc[mi][ni][r] - wsv * cwf[k * Dd + d];
        if (PM == 0) {
          Ep[(size_t)blockIdx.x * (Kk * Dd) + k * Dd + d] = v;
        } else {
          atomicAdd(out + (size_t)b * (Kk * Dd) + k * Dd + d, v);
        }
      }
    }
  }
}

// ---------------- k3: out = sum over 8 chunk-partials (16 floats/thread)
__global__ __launch_bounds__(256, 1) void enc_reduce_f32(
    const float* __restrict__ Ep, float* __restrict__ out) {
  const size_t i = ((size_t)blockIdx.x * 256 + threadIdx.x) * 16;
  const int b   = (int)(i / (Kk * Dd));
  const int rem = (int)(i % (Kk * Dd));
  const float* p = Ep + (size_t)b * CH2 * (Kk * Dd) + rem;
  float sx[16];
  #pragma unroll
  for (int j = 0; j < 16; ++j) sx[j] = 0.f;
  #pragma unroll
  for (int c = 0; c < CH2; ++c) {
    const float4* q = (const float4*)(p + (size_t)c * (Kk * Dd));
    float4 v0 = q[0], v1 = q[1], v2 = q[2], v3 = q[3];
    sx[0] += v0.x; sx[1] += v0.y; sx[2]  += v0.z; sx[3]  += v0.w;
    sx[4] += v1.x; sx[5] += v1.y; sx[6]  += v1.z; sx[7]  += v1.w;
    sx[8] += v2.x; sx[9] += v2.y; sx[10] += v2.z; sx[11] += v2.w;
    sx[12] += v3.x; sx[13] += v3.y; sx[14] += v3.z; sx[15] += v3.w;
  }
  float4* o = (float4*)(out + i);
  o[0] = make_float4(sx[0], sx[1], sx[2], sx[3]);
  o[1] = make_float4(sx[4], sx[5], sx[6], sx[7]);
  o[2] = make_float4(sx[8], sx[9], sx[10], sx[11]);
  o[3] = make_float4(sx[12], sx[13], sx[14], sx[15]);
}

extern "C" void kernel_launch(void* const* d_in, const int* in_sizes, int n_in,
                              void* d_out, int out_size, void* d_ws, size_t ws_size,
                              hipStream_t stream) {
  const float* x  = (const float*)d_in[0];   // (32, 4096, 256)
  const float* cw = (const float*)d_in[1];   // (128, 256)
  const float* sc = (const float*)d_in[2];   // (128,)
  float* out = (float*)d_out;                // (32, 128, 256)

  unsigned short* cbf = (unsigned short*)d_ws;                      // 64KB
  float2* tab = (float2*)((char*)d_ws + 65536);                     // 1KB
  unsigned short* Wt = (unsigned short*)((char*)d_ws + 66560);      // 33.55MB W^T bf16
  float* Ep = (float*)((char*)d_ws + 66560 + (size_t)32 * Kk * Nn * 2);  // 33.55MB fp32
  const size_t KD = (size_t)Kk * Dd;
  const size_t needFull = 66560 + (size_t)32 * Kk * Nn * 2 + (size_t)32 * CH2 * KD * 4; // 67,175,424 (== r8 proven)
  const size_t needAtm  = 66560 + (size_t)32 * Kk * Nn * 2;

  enc_prep<<<dim3(Kk), dim3(64), 0, stream>>>(cw, sc, cbf, tab);
  enc_w<<<dim3(32 * SEGS), dim3(1024), 0, stream>>>(x, cbf, tab, Wt);

  if (ws_size >= needFull) {
    enc_e<0><<<dim3(32 * CH2), dim3(1024), 0, stream>>>(x, Wt, cw, Ep, nullptr);
    enc_reduce_f32<<<dim3(256), dim3(256), 0, stream>>>(Ep, out);
  } else if (ws_size >= needAtm) {
    hipMemsetAsync(d_out, 0, (size_t)out_size * sizeof(float), stream);
    enc_e<2><<<dim3(32 * CH2), dim3(1024), 0, stream>>>(x, Wt, cw, nullptr, out);
  }
}

// Round 11
// 145.412 us; speedup vs baseline: 1.0003x; 1.0003x over previous
//
#include <hip/hip_runtime.h>

#define DEV __device__ __forceinline__

typedef __attribute__((ext_vector_type(8))) short bf16x8;
typedef __attribute__((ext_vector_type(4))) float f32x4;

constexpr int Nn = 4096, Dd = 256, Kk = 128;
constexpr int SEGS = 16;          // k1 segments per batch (256 rows each)
constexpr int CH2  = 8;           // k2 n-chunks per batch (512 rows each)
constexpr int NCH  = Nn / CH2;    // 512 rows per k2 block
constexpr int NSTEP = 64;         // k2 n-step

DEV unsigned short f2bf(float f) {
  unsigned int u = __builtin_bit_cast(unsigned int, f);
  u += 0x7FFFu + ((u >> 16) & 1u);          // RNE; inputs are finite
  return (unsigned short)(u >> 16);
}
DEV float bf2f(unsigned short h) {
  unsigned int u = (unsigned int)h << 16;
  return __builtin_bit_cast(float, u);
}

// k2 xT tile: row d = 128B (64 bf16 n-values). Swizzle 16B slot by
// hh(d) = (d&7)^((d>>4)&7)^(((d>>7)&1)<<1):
//  - staging writes (lane ln scatters d=ln*16+j): <=4-way (1.58x, writes only)
//  - b128 frag reads (lanes d=base+ln):           <=2-way (free)
DEV unsigned lds2(unsigned d, unsigned nbyte) {
  unsigned hh = (d & 7u) ^ ((d >> 4) & 7u) ^ (((d >> 7) & 1u) << 1);
  return d * 128u + (nbyte ^ (hh << 4));
}

__global__ void enc_prep(const float* __restrict__ cw, const float* __restrict__ sc,
                         unsigned short* __restrict__ cbf, float2* __restrict__ tab) {
  int k = blockIdx.x, l = threadIdx.x;          // 128 blocks x 64 threads
  float4 u = *(const float4*)(cw + k * Dd + l * 4);
  float s2 = u.x * u.x + u.y * u.y + u.z * u.z + u.w * u.w;
  #pragma unroll
  for (int o = 1; o < 64; o <<= 1) s2 += __shfl_xor(s2, o);
  unsigned short* dst = cbf + k * Dd + l * 4;
  dst[0] = f2bf(u.x); dst[1] = f2bf(u.y); dst[2] = f2bf(u.z); dst[3] = f2bf(u.w);
  if (l == 0) { float s = sc[k]; tab[k] = make_float2(s * s2, 2.0f * s); }
}

// ---------------- k1: W^T producer. Fully independent waves, no block sync
// after the 1KB tab stage. Each wave: 16 rows, S^T = mfma(c,x), softmax in
// registers, 32 bf16 stores of W^T[b][k][n].
__global__ __launch_bounds__(1024) void enc_w(
    const float* __restrict__ x, const unsigned short* __restrict__ cbf,
    const float2* __restrict__ tab, unsigned short* __restrict__ Wt) {
  __shared__ float2 tabL[Kk];
  const int tid = threadIdx.x;
  const int w  = tid >> 6;             // wave 0..15
  const int l  = tid & 63;
  const int g  = l >> 4;               // 16-lane group 0..3
  const int ln = l & 15;
  if (tid < Kk) tabL[tid] = tab[tid];
  __syncthreads();

  const int b   = blockIdx.x >> 4;     // 32 batches x 16 segments
  const int seg = blockIdx.x & 15;
  const int nrow = seg * 256 + w * 16 + ln;            // row within batch
  const float* xrow = x + ((size_t)b * Nn + nrow) * Dd;

  f32x4 s1[8];
  const f32x4 zero4 = {0.f, 0.f, 0.f, 0.f};
  #pragma unroll
  for (int f = 0; f < 8; ++f) s1[f] = zero4;
  float x2p = 0.f;

  #pragma unroll
  for (int ks = 0; ks < 8; ++ks) {
    const int d0 = ks * 32 + g * 8;
    float4 u0 = *(const float4*)(xrow + d0);
    float4 u1 = *(const float4*)(xrow + d0 + 4);
    x2p += u0.x*u0.x + u0.y*u0.y + u0.z*u0.z + u0.w*u0.w
         + u1.x*u1.x + u1.y*u1.y + u1.z*u1.z + u1.w*u1.w;
    bf16x8 xv;
    xv[0] = (short)f2bf(u0.x); xv[1] = (short)f2bf(u0.y);
    xv[2] = (short)f2bf(u0.z); xv[3] = (short)f2bf(u0.w);
    xv[4] = (short)f2bf(u1.x); xv[5] = (short)f2bf(u1.y);
    xv[6] = (short)f2bf(u1.z); xv[7] = (short)f2bf(u1.w);
    #pragma unroll
    for (int f = 0; f < 8; ++f) {
      bf16x8 a = *(const bf16x8*)(cbf + (f * 16 + ln) * Dd + d0);
      s1[f] = __builtin_amdgcn_mfma_f32_16x16x32_bf16(a, xv, s1[f], 0, 0, 0);
    }
  }

  x2p += __shfl_xor(x2p, 16); x2p += __shfl_xor(x2p, 32);
  const float hx2 = 0.5f * x2p;
  float ssum = 0.f;
  #pragma unroll
  for (int f = 0; f < 8; ++f) {
    #pragma unroll
    for (int r = 0; r < 4; ++r) {
      const float2 ab = tabL[f * 16 + g * 4 + r];
      const float ev = __expf(ab.x + ab.y * (hx2 - s1[f][r]));
      s1[f][r] = ev;
      ssum += ev;
    }
  }
  ssum += __shfl_xor(ssum, 16); ssum += __shfl_xor(ssum, 32);
  const float rinv = 1.0f / ssum;

  unsigned short* wb = Wt + (size_t)b * Kk * Nn + nrow;
  #pragma unroll
  for (int f = 0; f < 8; ++f) {
    #pragma unroll
    for (int r = 0; r < 4; ++r) {
      const int cwi = f * 16 + g * 4 + r;
      wb[(size_t)cwi * Nn] = f2bf(s1[f][r] * rinv);
    }
  }
}

// ---------------- k2: Ep_chunk[k][d] = sum_n W^T[k][n] x[n][d] - Wsum_chunk[k] c[k][d]
// Double-buffered LDS xT, T14 issue-early/write-late staging, W frags from L2,
// Wsum accumulated from A-fragments in-register. PM: 0 = fp32 partials, 2 = atomic.
template<int PM>
__global__ __launch_bounds__(1024) void enc_e(
    const float* __restrict__ x, const unsigned short* __restrict__ Wt,
    const float* __restrict__ cwf, float* __restrict__ Ep, float* __restrict__ out) {
  __shared__ __align__(16) char xs[2 * 32768];   // xT [256 d][64 n] bf16, dbuf
  __shared__ float wsL[Kk];

  const int tid = threadIdx.x;
  const int w  = tid >> 6;             // wave 0..15
  const int l  = tid & 63;
  const int g  = l >> 4;
  const int ln = l & 15;
  const int wr = w >> 2, wc = w & 3;   // 4x4 wave grid over E(128k x 256d)
  const int b  = blockIdx.x >> 3, ch = blockIdx.x & 7;

  const float* xb = x + ((size_t)b * Nn + ch * NCH) * Dd;
  const unsigned short* Wb = Wt + (size_t)b * Kk * Nn + ch * NCH;

  // staging role: row n_loc = w*4+g (0..63), d-slice = ln*16..+15 (16 floats)
  const int srow = w * 4 + g;
  const int sd0  = ln * 16;
  const unsigned swz0 = lds2((unsigned)(sd0 + 0), (unsigned)(srow * 2)) & 0x7fu; // per-d base varies; compute inline below

  f32x4 acc[2][4];
  const f32x4 zero4 = {0.f, 0.f, 0.f, 0.f};
  #pragma unroll
  for (int mi = 0; mi < 2; ++mi)
    #pragma unroll
    for (int ni = 0; ni < 4; ++ni) acc[mi][ni] = zero4;
  float ws0 = 0.f, ws1 = 0.f;

  // prologue: stage step 0 into buf 0
  {
    const float* p = xb + (size_t)srow * Dd + sd0;
    float4 u0 = *(const float4*)(p + 0), u1 = *(const float4*)(p + 4);
    float4 u2 = *(const float4*)(p + 8), u3 = *(const float4*)(p + 12);
    const float uu[16] = {u0.x,u0.y,u0.z,u0.w, u1.x,u1.y,u1.z,u1.w,
                          u2.x,u2.y,u2.z,u2.w, u3.x,u3.y,u3.z,u3.w};
    #pragma unroll
    for (int j = 0; j < 16; ++j)
      *(unsigned short*)(xs + lds2((unsigned)(sd0 + j), (unsigned)(srow * 2))) = f2bf(uu[j]);
  }
  __syncthreads();

  int cur = 0;
  for (int s = 0; s < CH2; ++s) {          // 8 n-steps of 64
    // T14: issue next step's global loads before compute
    float4 n0, n1, n2, n3;
    if (s + 1 < CH2) {
      const float* p = xb + (size_t)((s + 1) * NSTEP + srow) * Dd + sd0;
      n0 = *(const float4*)(p + 0); n1 = *(const float4*)(p + 4);
      n2 = *(const float4*)(p + 8); n3 = *(const float4*)(p + 12);
    }

    const char* xcur = xs + (cur << 15);
    #pragma unroll
    for (int ks2 = 0; ks2 < 2; ++ks2) {
      const int ncol = s * NSTEP + ks2 * 32 + g * 8;     // within-chunk n of this frag
      bf16x8 af[2], bg[4];
      #pragma unroll
      for (int mi = 0; mi < 2; ++mi)
        af[mi] = *(const bf16x8*)(Wb + (size_t)(wr * 32 + mi * 16 + ln) * Nn + ncol);
      #pragma unroll
      for (int ni = 0; ni < 4; ++ni)
        bg[ni] = *(const bf16x8*)(xcur + lds2((unsigned)(wc * 64 + ni * 16 + ln),
                                              (unsigned)((ks2 * 32 + g * 8) * 2)));
      #pragma unroll
      for (int mi = 0; mi < 2; ++mi) {
        float wsp = 0.f;
        #pragma unroll
        for (int j = 0; j < 8; ++j) wsp += bf2f((unsigned short)af[mi][j]);
        if (mi == 0) ws0 += wsp; else ws1 += wsp;
        #pragma unroll
        for (int ni = 0; ni < 4; ++ni)
          acc[mi][ni] = __builtin_amdgcn_mfma_f32_16x16x32_bf16(af[mi], bg[ni], acc[mi][ni], 0, 0, 0);
      }
    }
    __syncthreads();                        // everyone done reading xs[cur^1]'s successor safely
    if (s + 1 < CH2) {
      char* xn = xs + ((cur ^ 1) << 15);
      const float uu[16] = {n0.x,n0.y,n0.z,n0.w, n1.x,n1.y,n1.z,n1.w,
                            n2.x,n2.y,n2.z,n2.w, n3.x,n3.y,n3.z,n3.w};
      #pragma unroll
      for (int j = 0; j < 16; ++j)
        *(unsigned short*)(xn + lds2((unsigned)(sd0 + j), (unsigned)(srow * 2))) = f2bf(uu[j]);
    }
    __syncthreads();
    cur ^= 1;
  }

  // Wsum_chunk[k]: reduce across g (frags covered disjoint n-slices), publish once
  ws0 += __shfl_xor(ws0, 16); ws0 += __shfl_xor(ws0, 32);
  ws1 += __shfl_xor(ws1, 16); ws1 += __shfl_xor(ws1, 32);
  if (wc == 0 && l < 16) {
    wsL[wr * 32 + l]      = ws0;
    wsL[wr * 32 + 16 + l] = ws1;
  }
  __syncthreads();

  #pragma unroll
  for (int mi = 0; mi < 2; ++mi) {
    #pragma unroll
    for (int r = 0; r < 4; ++r) {
      const int k = wr * 32 + mi * 16 + g * 4 + r;
      const float wsv = wsL[k];
      #pragma unroll
      for (int ni = 0; ni < 4; ++ni) {
        const int d = wc * 64 + ni * 16 + ln;
        const float v = acc[mi][ni][r] - wsv * cwf[k * Dd + d];
        if (PM == 0) {
          Ep[(size_t)blockIdx.x * (Kk * Dd) + k * Dd + d] = v;
        } else {
          atomicAdd(out + (size_t)b * (Kk * Dd) + k * Dd + d, v);
        }
      }
    }
  }
}

// ---------------- k3: out = sum over 8 chunk-partials (16 floats/thread)
__global__ __launch_bounds__(256, 1) void enc_reduce_f32(
    const float* __restrict__ Ep, float* __restrict__ out) {
  const size_t i = ((size_t)blockIdx.x * 256 + threadIdx.x) * 16;
  const int b   = (int)(i / (Kk * Dd));
  const int rem = (int)(i % (Kk * Dd));
  const float* p = Ep + (size_t)b * CH2 * (Kk * Dd) + rem;
  float sx[16];
  #pragma unroll
  for (int j = 0; j < 16; ++j) sx[j] = 0.f;
  #pragma unroll
  for (int c = 0; c < CH2; ++c) {
    const float4* q = (const float4*)(p + (size_t)c * (Kk * Dd));
    float4 v0 = q[0], v1 = q[1], v2 = q[2], v3 = q[3];
    sx[0] += v0.x; sx[1] += v0.y; sx[2]  += v0.z; sx[3]  += v0.w;
    sx[4] += v1.x; sx[5] += v1.y; sx[6]  += v1.z; sx[7]  += v1.w;
    sx[8] += v2.x; sx[9] += v2.y; sx[10] += v2.z; sx[11] += v2.w;
    sx[12] += v3.x; sx[13] += v3.y; sx[14] += v3.z; sx[15] += v3.w;
  }
  float4* o = (float4*)(out + i);
  o[0] = make_float4(sx[0], sx[1], sx[2], sx[3]);
  o[1] = make_float4(sx[4], sx[5], sx[6], sx[7]);
  o[2] = make_float4(sx[8], sx[9], sx[10], sx[11]);
  o[3] = make_float4(sx[12], sx[13], sx[14], sx[15]);
}

extern "C" void kernel_launch(void* const* d_in, const int* in_sizes, int n_in,
                              void* d_out, int out_size, void* d_ws, size_t ws_size,
                              hipStream_t stream) {
  const float* x  = (const float*)d_in[0];   // (32, 4096, 256)
  const float* cw = (const float*)d_in[1];   // (128, 256)
  const float* sc = (const float*)d_in[2];   // (128,)
  float* out = (float*)d_out;                // (32, 128, 256)

  unsigned short* cbf = (unsigned short*)d_ws;                      // 64KB
  float2* tab = (float2*)((char*)d_ws + 65536);                     // 1KB
  unsigned short* Wt = (unsigned short*)((char*)d_ws + 66560);      // 33.55MB W^T bf16
  float* Ep = (float*)((char*)d_ws + 66560 + (size_t)32 * Kk * Nn * 2);  // 33.55MB fp32
  const size_t KD = (size_t)Kk * Dd;
  const size_t needFull = 66560 + (size_t)32 * Kk * Nn * 2 + (size_t)32 * CH2 * KD * 4; // 67,175,424 (== r8 proven)
  const size_t needAtm  = 66560 + (size_t)32 * Kk * Nn * 2;

  enc_prep<<<dim3(Kk), dim3(64), 0, stream>>>(cw, sc, cbf, tab);
  enc_w<<<dim3(32 * SEGS), dim3(1024), 0, stream>>>(x, cbf, tab, Wt);

  if (ws_size >= needFull) {
    enc_e<0><<<dim3(32 * CH2), dim3(1024), 0, stream>>>(x, Wt, cw, Ep, nullptr);
    enc_reduce_f32<<<dim3(256), dim3(256), 0, stream>>>(Ep, out);
  } else if (ws_size >= needAtm) {
    hipMemsetAsync(d_out, 0, (size_t)out_size * sizeof(float), stream);
    enc_e<2><<<dim3(32 * CH2), dim3(1024), 0, stream>>>(x, Wt, cw, nullptr, out);
  }
}

// Round 12
// 105.559 us; speedup vs baseline: 1.3779x; 1.3775x over previous
//
#include <hip/hip_runtime.h>

#define DEV __device__ __forceinline__

typedef __attribute__((ext_vector_type(8))) short bf16x8;
typedef __attribute__((ext_vector_type(4))) float f32x4;

constexpr int Nn = 4096, Dd = 256, Kk = 128;
constexpr int SEGS = 32;          // k1 segments per batch (128 rows each)
constexpr int CH2  = 8;           // k2 n-chunks per batch (512 rows each)
constexpr int NCH  = Nn / CH2;    // 512 rows per k2 block
constexpr int NSTEP = 64;         // k2 n-step

DEV unsigned short f2bf(float f) {
  unsigned int u = __builtin_bit_cast(unsigned int, f);
  u += 0x7FFFu + ((u >> 16) & 1u);          // RNE; inputs are finite
  return (unsigned short)(u >> 16);
}
DEV float bf2f(unsigned short h) {
  unsigned int u = (unsigned int)h << 16;
  return __builtin_bit_cast(float, u);
}

// k2 xT tile: row d = 128B (64 bf16 n-values). Swizzle 16B slot by
// hh(d) = (d&7)^((d>>4)&7)^(((d>>7)&1)<<1):
//  - staging writes (lane ln scatters d=ln*16+j): <=4-way (1.58x, writes only)
//  - b128 frag reads (lanes d=base+ln):           <=2-way (free)
DEV unsigned lds2(unsigned d, unsigned nbyte) {
  unsigned hh = (d & 7u) ^ ((d >> 4) & 7u) ^ (((d >> 7) & 1u) << 1);
  return d * 128u + (nbyte ^ (hh << 4));
}

// k1 cbf LDS tile: row k = 512B (256 bf16 d-values). XOR byte bits 4-6 by
// (row&7): the 16-row x 4-slice b128 frag read spreads uniformly over the 8
// bank-quads (8 chunks/quad = the 1024B/instr floor). Same formula on both
// write and read sides.
DEV unsigned ldsc(unsigned row, unsigned byteInRow) {
  return row * 512u + (byteInRow ^ ((row & 7u) << 4));
}

__global__ void enc_prep(const float* __restrict__ cw, const float* __restrict__ sc,
                         unsigned short* __restrict__ cbf, float2* __restrict__ tab) {
  int k = blockIdx.x, l = threadIdx.x;          // 128 blocks x 64 threads
  float4 u = *(const float4*)(cw + k * Dd + l * 4);
  float s2 = u.x * u.x + u.y * u.y + u.z * u.z + u.w * u.w;
  #pragma unroll
  for (int o = 1; o < 64; o <<= 1) s2 += __shfl_xor(s2, o);
  unsigned short* dst = cbf + k * Dd + l * 4;
  dst[0] = f2bf(u.x); dst[1] = f2bf(u.y); dst[2] = f2bf(u.z); dst[3] = f2bf(u.w);
  if (l == 0) { float s = sc[k]; tab[k] = make_float2(s * s2, 2.0f * s); }
}

// ---------------- k1: W^T producer. 512 thr / (512,1) -> 128-VGPR budget so the
// distance-4 rotating x-prefetch (8-14 loads in flight/wave) actually fits.
// cbf lives in swizzled LDS: zero vmcnt pressure from the A-operand.
__global__ __launch_bounds__(512, 1) void enc_w(
    const float* __restrict__ x, const unsigned short* __restrict__ cbf,
    const float2* __restrict__ tab, unsigned short* __restrict__ Wt) {
  __shared__ __align__(16) char cL[65536];
  __shared__ float2 tabL[Kk];
  const int tid = threadIdx.x;
  const int w  = tid >> 6;             // wave 0..7
  const int l  = tid & 63;
  const int g  = l >> 4;               // 16-lane group 0..3
  const int ln = l & 15;

  // stage cbf -> swizzled LDS: thread i copies 128B (row i/4, quarter i%4)
  {
    const int r = tid >> 2, part = tid & 3;
    const char* src = (const char*)cbf + r * 512 + part * 128;
    #pragma unroll
    for (int j = 0; j < 8; ++j) {
      float4 v = *(const float4*)(src + j * 16);
      *(float4*)(cL + ldsc((unsigned)r, (unsigned)(part * 128 + j * 16))) = v;
    }
  }
  if (tid < Kk) tabL[tid] = tab[tid];
  __syncthreads();

  const int b   = blockIdx.x >> 5;     // 32 batches x 32 segments
  const int seg = blockIdx.x & 31;
  const int nrow = seg * 128 + w * 16 + ln;            // row within batch
  const float* xrow = x + ((size_t)b * Nn + nrow) * Dd;

  f32x4 s1[8];
  const f32x4 zero4 = {0.f, 0.f, 0.f, 0.f};
  #pragma unroll
  for (int f = 0; f < 8; ++f) s1[f] = zero4;
  float x2p = 0.f;

  // distance-4 rotating prefetch of this lane's 16 float4 slices
  float4 pu[4][2];
  #pragma unroll
  for (int p = 0; p < 4; ++p) {
    pu[p][0] = *(const float4*)(xrow + p * 32 + g * 8);
    pu[p][1] = *(const float4*)(xrow + p * 32 + g * 8 + 4);
  }

  #pragma unroll
  for (int ks = 0; ks < 8; ++ks) {
    float4 u0 = pu[ks & 3][0], u1 = pu[ks & 3][1];
    if (ks + 4 < 8) {
      pu[ks & 3][0] = *(const float4*)(xrow + (ks + 4) * 32 + g * 8);
      pu[ks & 3][1] = *(const float4*)(xrow + (ks + 4) * 32 + g * 8 + 4);
    }
    x2p += u0.x*u0.x + u0.y*u0.y + u0.z*u0.z + u0.w*u0.w
         + u1.x*u1.x + u1.y*u1.y + u1.z*u1.z + u1.w*u1.w;
    bf16x8 xv;
    xv[0] = (short)f2bf(u0.x); xv[1] = (short)f2bf(u0.y);
    xv[2] = (short)f2bf(u0.z); xv[3] = (short)f2bf(u0.w);
    xv[4] = (short)f2bf(u1.x); xv[5] = (short)f2bf(u1.y);
    xv[6] = (short)f2bf(u1.z); xv[7] = (short)f2bf(u1.w);
    const unsigned colb = (unsigned)(ks * 64 + g * 16);
    #pragma unroll
    for (int f = 0; f < 8; ++f) {
      bf16x8 a = *(const bf16x8*)(cL + ldsc((unsigned)(f * 16 + ln), colb));
      s1[f] = __builtin_amdgcn_mfma_f32_16x16x32_bf16(a, xv, s1[f], 0, 0, 0);
    }
  }

  x2p += __shfl_xor(x2p, 16); x2p += __shfl_xor(x2p, 32);
  const float hx2 = 0.5f * x2p;
  float ssum = 0.f;
  #pragma unroll
  for (int f = 0; f < 8; ++f) {
    #pragma unroll
    for (int r = 0; r < 4; ++r) {
      const float2 ab = tabL[f * 16 + g * 4 + r];
      const float ev = __expf(ab.x + ab.y * (hx2 - s1[f][r]));
      s1[f][r] = ev;
      ssum += ev;
    }
  }
  ssum += __shfl_xor(ssum, 16); ssum += __shfl_xor(ssum, 32);
  const float rinv = 1.0f / ssum;

  unsigned short* wb = Wt + (size_t)b * Kk * Nn + nrow;
  #pragma unroll
  for (int f = 0; f < 8; ++f) {
    #pragma unroll
    for (int r = 0; r < 4; ++r) {
      const int cwi = f * 16 + g * 4 + r;
      wb[(size_t)cwi * Nn] = f2bf(s1[f][r] * rinv);
    }
  }
}

// ---------------- k2: Ep_chunk[k][d] = sum_n W^T[k][n] x[n][d] - Wsum_chunk[k] c[k][d]
// Double-buffered LDS xT, issue-early/write-late staging, W frags from L2,
// Wsum accumulated from A-fragments in-register. PM: 0 = fp32 partials, 2 = atomic.
template<int PM>
__global__ __launch_bounds__(1024) void enc_e(
    const float* __restrict__ x, const unsigned short* __restrict__ Wt,
    const float* __restrict__ cwf, float* __restrict__ Ep, float* __restrict__ out) {
  __shared__ __align__(16) char xs[2 * 32768];   // xT [256 d][64 n] bf16, dbuf
  __shared__ float wsL[Kk];

  const int tid = threadIdx.x;
  const int w  = tid >> 6;             // wave 0..15
  const int l  = tid & 63;
  const int g  = l >> 4;
  const int ln = l & 15;
  const int wr = w >> 2, wc = w & 3;   // 4x4 wave grid over E(128k x 256d)
  const int b  = blockIdx.x >> 3, ch = blockIdx.x & 7;

  const float* xb = x + ((size_t)b * Nn + ch * NCH) * Dd;
  const unsigned short* Wb = Wt + (size_t)b * Kk * Nn + ch * NCH;

  // staging role: row n_loc = w*4+g (0..63), d-slice = ln*16..+15 (16 floats)
  const int srow = w * 4 + g;
  const int sd0  = ln * 16;

  f32x4 acc[2][4];
  const f32x4 zero4 = {0.f, 0.f, 0.f, 0.f};
  #pragma unroll
  for (int mi = 0; mi < 2; ++mi)
    #pragma unroll
    for (int ni = 0; ni < 4; ++ni) acc[mi][ni] = zero4;
  float ws0 = 0.f, ws1 = 0.f;

  // prologue: stage step 0 into buf 0
  {
    const float* p = xb + (size_t)srow * Dd + sd0;
    float4 u0 = *(const float4*)(p + 0), u1 = *(const float4*)(p + 4);
    float4 u2 = *(const float4*)(p + 8), u3 = *(const float4*)(p + 12);
    const float uu[16] = {u0.x,u0.y,u0.z,u0.w, u1.x,u1.y,u1.z,u1.w,
                          u2.x,u2.y,u2.z,u2.w, u3.x,u3.y,u3.z,u3.w};
    #pragma unroll
    for (int j = 0; j < 16; ++j)
      *(unsigned short*)(xs + lds2((unsigned)(sd0 + j), (unsigned)(srow * 2))) = f2bf(uu[j]);
  }
  __syncthreads();

  int cur = 0;
  for (int s = 0; s < CH2; ++s) {          // 8 n-steps of 64
    // issue next step's global loads before compute
    float4 n0, n1, n2, n3;
    if (s + 1 < CH2) {
      const float* p = xb + (size_t)((s + 1) * NSTEP + srow) * Dd + sd0;
      n0 = *(const float4*)(p + 0); n1 = *(const float4*)(p + 4);
      n2 = *(const float4*)(p + 8); n3 = *(const float4*)(p + 12);
    }

    const char* xcur = xs + (cur << 15);
    #pragma unroll
    for (int ks2 = 0; ks2 < 2; ++ks2) {
      const int ncol = s * NSTEP + ks2 * 32 + g * 8;     // within-chunk n of this frag
      bf16x8 af[2], bg[4];
      #pragma unroll
      for (int mi = 0; mi < 2; ++mi)
        af[mi] = *(const bf16x8*)(Wb + (size_t)(wr * 32 + mi * 16 + ln) * Nn + ncol);
      #pragma unroll
      for (int ni = 0; ni < 4; ++ni)
        bg[ni] = *(const bf16x8*)(xcur + lds2((unsigned)(wc * 64 + ni * 16 + ln),
                                              (unsigned)((ks2 * 32 + g * 8) * 2)));
      #pragma unroll
      for (int mi = 0; mi < 2; ++mi) {
        float wsp = 0.f;
        #pragma unroll
        for (int j = 0; j < 8; ++j) wsp += bf2f((unsigned short)af[mi][j]);
        if (mi == 0) ws0 += wsp; else ws1 += wsp;
        #pragma unroll
        for (int ni = 0; ni < 4; ++ni)
          acc[mi][ni] = __builtin_amdgcn_mfma_f32_16x16x32_bf16(af[mi], bg[ni], acc[mi][ni], 0, 0, 0);
      }
    }
    __syncthreads();
    if (s + 1 < CH2) {
      char* xn = xs + ((cur ^ 1) << 15);
      const float uu[16] = {n0.x,n0.y,n0.z,n0.w, n1.x,n1.y,n1.z,n1.w,
                            n2.x,n2.y,n2.z,n2.w, n3.x,n3.y,n3.z,n3.w};
      #pragma unroll
      for (int j = 0; j < 16; ++j)
        *(unsigned short*)(xn + lds2((unsigned)(sd0 + j), (unsigned)(srow * 2))) = f2bf(uu[j]);
    }
    __syncthreads();
    cur ^= 1;
  }

  // Wsum_chunk[k]: reduce across g (frags covered disjoint n-slices), publish once
  ws0 += __shfl_xor(ws0, 16); ws0 += __shfl_xor(ws0, 32);
  ws1 += __shfl_xor(ws1, 16); ws1 += __shfl_xor(ws1, 32);
  if (wc == 0 && l < 16) {
    wsL[wr * 32 + l]      = ws0;
    wsL[wr * 32 + 16 + l] = ws1;
  }
  __syncthreads();

  #pragma unroll
  for (int mi = 0; mi < 2; ++mi) {
    #pragma unroll
    for (int r = 0; r < 4; ++r) {
      const int k = wr * 32 + mi * 16 + g * 4 + r;
      const float wsv = wsL[k];
      #pragma unroll
      for (int ni = 0; ni < 4; ++ni) {
        const int d = wc * 64 + ni * 16 + ln;
        const float v = acc[mi][ni][r] - wsv * cwf[k * Dd + d];
        if (PM == 0) {
          Ep[(size_t)blockIdx.x * (Kk * Dd) + k * Dd + d] = v;
        } else {
          atomicAdd(out + (size_t)b * (Kk * Dd) + k * Dd + d, v);
        }
      }
    }
  }
}

// ---------------- k3: out = sum over 8 chunk-partials (16 floats/thread)
__global__ __launch_bounds__(256, 1) void enc_reduce_f32(
    const float* __restrict__ Ep, float* __restrict__ out) {
  const size_t i = ((size_t)blockIdx.x * 256 + threadIdx.x) * 16;
  const int b   = (int)(i / (Kk * Dd));
  const int rem = (int)(i % (Kk * Dd));
  const float* p = Ep + (size_t)b * CH2 * (Kk * Dd) + rem;
  float sx[16];
  #pragma unroll
  for (int j = 0; j < 16; ++j) sx[j] = 0.f;
  #pragma unroll
  for (int c = 0; c < CH2; ++c) {
    const float4* q = (const float4*)(p + (size_t)c * (Kk * Dd));
    float4 v0 = q[0], v1 = q[1], v2 = q[2], v3 = q[3];
    sx[0] += v0.x; sx[1] += v0.y; sx[2]  += v0.z; sx[3]  += v0.w;
    sx[4] += v1.x; sx[5] += v1.y; sx[6]  += v1.z; sx[7]  += v1.w;
    sx[8] += v2.x; sx[9] += v2.y; sx[10] += v2.z; sx[11] += v2.w;
    sx[12] += v3.x; sx[13] += v3.y; sx[14] += v3.z; sx[15] += v3.w;
  }
  float4* o = (float4*)(out + i);
  o[0] = make_float4(sx[0], sx[1], sx[2], sx[3]);
  o[1] = make_float4(sx[4], sx[5], sx[6], sx[7]);
  o[2] = make_float4(sx[8], sx[9], sx[10], sx[11]);
  o[3] = make_float4(sx[12], sx[13], sx[14], sx[15]);
}

extern "C" void kernel_launch(void* const* d_in, const int* in_sizes, int n_in,
                              void* d_out, int out_size, void* d_ws, size_t ws_size,
                              hipStream_t stream) {
  const float* x  = (const float*)d_in[0];   // (32, 4096, 256)
  const float* cw = (const float*)d_in[1];   // (128, 256)
  const float* sc = (const float*)d_in[2];   // (128,)
  float* out = (float*)d_out;                // (32, 128, 256)

  unsigned short* cbf = (unsigned short*)d_ws;                      // 64KB
  float2* tab = (float2*)((char*)d_ws + 65536);                     // 1KB
  unsigned short* Wt = (unsigned short*)((char*)d_ws + 66560);      // 33.55MB W^T bf16
  float* Ep = (float*)((char*)d_ws + 66560 + (size_t)32 * Kk * Nn * 2);  // 33.55MB fp32
  const size_t KD = (size_t)Kk * Dd;
  const size_t needFull = 66560 + (size_t)32 * Kk * Nn * 2 + (size_t)32 * CH2 * KD * 4;
  const size_t needAtm  = 66560 + (size_t)32 * Kk * Nn * 2;

  enc_prep<<<dim3(Kk), dim3(64), 0, stream>>>(cw, sc, cbf, tab);
  enc_w<<<dim3(32 * SEGS), dim3(512), 0, stream>>>(x, cbf, tab, Wt);

  if (ws_size >= needFull) {
    enc_e<0><<<dim3(32 * CH2), dim3(1024), 0, stream>>>(x, Wt, cw, Ep, nullptr);
    enc_reduce_f32<<<dim3(256), dim3(256), 0, stream>>>(Ep, out);
  } else if (ws_size >= needAtm) {
    hipMemsetAsync(d_out, 0, (size_t)out_size * sizeof(float), stream);
    enc_e<2><<<dim3(32 * CH2), dim3(1024), 0, stream>>>(x, Wt, cw, nullptr, out);
  }
}

// Round 13
// 99.332 us; speedup vs baseline: 1.4643x; 1.0627x over previous
//
#include <hip/hip_runtime.h>

#define DEV __device__ __forceinline__

typedef __attribute__((ext_vector_type(8))) short bf16x8;
typedef __attribute__((ext_vector_type(4))) float f32x4;

constexpr int Nn = 4096, Dd = 256, Kk = 128;
constexpr int SEGS = 32;          // k1 segments per batch (128 rows each)
constexpr int CH2  = 8;           // k2 n-chunks per batch (512 rows each)
constexpr int NCH  = Nn / CH2;    // 512 rows per k2 block
constexpr int NSTEP = 64;         // k2 n-step

DEV unsigned short f2bf(float f) {
  unsigned int u = __builtin_bit_cast(unsigned int, f);
  u += 0x7FFFu + ((u >> 16) & 1u);          // RNE; inputs are finite
  return (unsigned short)(u >> 16);
}
DEV float bf2f(unsigned short h) {
  unsigned int u = (unsigned int)h << 16;
  return __builtin_bit_cast(float, u);
}

// k2 xT tile: row d = 128B (64 bf16 n-values). Swizzle 16B slot by
// hh(d) = (d&7)^((d>>4)&7)^(((d>>7)&1)<<1):
//  - staging writes (lane ln scatters d=ln*16+j): <=4-way (1.58x, writes only)
//  - b128 frag reads (lanes d=base+ln):           <=2-way (free)
DEV unsigned lds2(unsigned d, unsigned nbyte) {
  unsigned hh = (d & 7u) ^ ((d >> 4) & 7u) ^ (((d >> 7) & 1u) << 1);
  return d * 128u + (nbyte ^ (hh << 4));
}

// k1 cbf LDS tile: row k = 512B (256 bf16 d-values). XOR byte bits 4-6 by
// (row&7): the 16-row b128 frag read spreads across the 8 bank-quads.
DEV unsigned ldsc(unsigned row, unsigned byteInRow) {
  return row * 512u + (byteInRow ^ ((row & 7u) << 4));
}

__global__ void enc_prep(const float* __restrict__ cw, const float* __restrict__ sc,
                         unsigned short* __restrict__ cbf, float2* __restrict__ tab) {
  int k = blockIdx.x, l = threadIdx.x;          // 128 blocks x 64 threads
  float4 u = *(const float4*)(cw + k * Dd + l * 4);
  float s2 = u.x * u.x + u.y * u.y + u.z * u.z + u.w * u.w;
  #pragma unroll
  for (int o = 1; o < 64; o <<= 1) s2 += __shfl_xor(s2, o);
  unsigned short* dst = cbf + k * Dd + l * 4;
  dst[0] = f2bf(u.x); dst[1] = f2bf(u.y); dst[2] = f2bf(u.z); dst[3] = f2bf(u.w);
  if (l == 0) { float s = sc[k]; tab[k] = make_float2(s * s2, 2.0f * s); }
}

// ---------------- k1: W^T producer. Full-row prefetch: all 16 float4 loads
// issued in the prologue (64 payload VGPRs; no accumulator array live, so the
// 128-VGPR budget of (512,1) holds it). cbf in swizzled LDS.
__global__ __launch_bounds__(512, 1) void enc_w(
    const float* __restrict__ x, const unsigned short* __restrict__ cbf,
    const float2* __restrict__ tab, unsigned short* __restrict__ Wt) {
  __shared__ __align__(16) char cL[65536];
  __shared__ float2 tabL[Kk];
  const int tid = threadIdx.x;
  const int w  = tid >> 6;             // wave 0..7
  const int l  = tid & 63;
  const int g  = l >> 4;               // 16-lane group 0..3
  const int ln = l & 15;

  // stage cbf -> swizzled LDS: thread i copies 128B (row i/4, quarter i%4)
  {
    const int r = tid >> 2, part = tid & 3;
    const char* src = (const char*)cbf + r * 512 + part * 128;
    #pragma unroll
    for (int j = 0; j < 8; ++j) {
      float4 v = *(const float4*)(src + j * 16);
      *(float4*)(cL + ldsc((unsigned)r, (unsigned)(part * 128 + j * 16))) = v;
    }
  }
  if (tid < Kk) tabL[tid] = tab[tid];
  __syncthreads();

  const int b   = blockIdx.x >> 5;     // 32 batches x 32 segments
  const int seg = blockIdx.x & 31;
  const int nrow = seg * 128 + w * 16 + ln;            // row within batch
  const float* xrow = x + ((size_t)b * Nn + nrow) * Dd;

  f32x4 s1[8];
  const f32x4 zero4 = {0.f, 0.f, 0.f, 0.f};
  #pragma unroll
  for (int f = 0; f < 8; ++f) s1[f] = zero4;
  float x2p = 0.f;

  // full-row prefetch: 16 independent loads in flight before any consumption
  float4 pu[8][2];
  #pragma unroll
  for (int p = 0; p < 8; ++p) {
    pu[p][0] = *(const float4*)(xrow + p * 32 + g * 8);
    pu[p][1] = *(const float4*)(xrow + p * 32 + g * 8 + 4);
  }

  #pragma unroll
  for (int ks = 0; ks < 8; ++ks) {
    float4 u0 = pu[ks][0], u1 = pu[ks][1];
    x2p += u0.x*u0.x + u0.y*u0.y + u0.z*u0.z + u0.w*u0.w
         + u1.x*u1.x + u1.y*u1.y + u1.z*u1.z + u1.w*u1.w;
    bf16x8 xv;
    xv[0] = (short)f2bf(u0.x); xv[1] = (short)f2bf(u0.y);
    xv[2] = (short)f2bf(u0.z); xv[3] = (short)f2bf(u0.w);
    xv[4] = (short)f2bf(u1.x); xv[5] = (short)f2bf(u1.y);
    xv[6] = (short)f2bf(u1.z); xv[7] = (short)f2bf(u1.w);
    const unsigned colb = (unsigned)(ks * 64 + g * 16);
    #pragma unroll
    for (int f = 0; f < 8; ++f) {
      bf16x8 a = *(const bf16x8*)(cL + ldsc((unsigned)(f * 16 + ln), colb));
      s1[f] = __builtin_amdgcn_mfma_f32_16x16x32_bf16(a, xv, s1[f], 0, 0, 0);
    }
  }

  x2p += __shfl_xor(x2p, 16); x2p += __shfl_xor(x2p, 32);
  const float hx2 = 0.5f * x2p;
  float ssum = 0.f;
  #pragma unroll
  for (int f = 0; f < 8; ++f) {
    #pragma unroll
    for (int r = 0; r < 4; ++r) {
      const float2 ab = tabL[f * 16 + g * 4 + r];
      const float ev = __expf(ab.x + ab.y * (hx2 - s1[f][r]));
      s1[f][r] = ev;
      ssum += ev;
    }
  }
  ssum += __shfl_xor(ssum, 16); ssum += __shfl_xor(ssum, 32);
  const float rinv = 1.0f / ssum;

  unsigned short* wb = Wt + (size_t)b * Kk * Nn + nrow;
  #pragma unroll
  for (int f = 0; f < 8; ++f) {
    #pragma unroll
    for (int r = 0; r < 4; ++r) {
      const int cwi = f * 16 + g * 4 + r;
      wb[(size_t)cwi * Nn] = f2bf(s1[f][r] * rinv);
    }
  }
}

// ---------------- k2: Ep_chunk[k][d] = sum_n W^T[k][n] x[n][d] - Wsum_chunk[k] c[k][d]
// Double-buffered LDS xT, issue-early/write-late staging, W frags prefetched one
// step ahead in registers, ONE barrier per step (writes hit the opposite buffer,
// so the mid-compute barrier orders nothing the end barrier doesn't already).
template<int PM>
__global__ __launch_bounds__(1024) void enc_e(
    const float* __restrict__ x, const unsigned short* __restrict__ Wt,
    const float* __restrict__ cwf, float* __restrict__ Ep, float* __restrict__ out) {
  __shared__ __align__(16) char xs[2 * 32768];   // xT [256 d][64 n] bf16, dbuf
  __shared__ float wsL[Kk];

  const int tid = threadIdx.x;
  const int w  = tid >> 6;             // wave 0..15
  const int l  = tid & 63;
  const int g  = l >> 4;
  const int ln = l & 15;
  const int wr = w >> 2, wc = w & 3;   // 4x4 wave grid over E(128k x 256d)
  const int b  = blockIdx.x >> 3, ch = blockIdx.x & 7;

  const float* xb = x + ((size_t)b * Nn + ch * NCH) * Dd;
  const unsigned short* Wb = Wt + (size_t)b * Kk * Nn + ch * NCH;

  // staging role: row n_loc = w*4+g (0..63), d-slice = ln*16..+15 (16 floats)
  const int srow = w * 4 + g;
  const int sd0  = ln * 16;

  f32x4 acc[2][4];
  const f32x4 zero4 = {0.f, 0.f, 0.f, 0.f};
  #pragma unroll
  for (int mi = 0; mi < 2; ++mi)
    #pragma unroll
    for (int ni = 0; ni < 4; ++ni) acc[mi][ni] = zero4;
  float ws0 = 0.f, ws1 = 0.f;

  // prologue: stage step 0 into buf 0; prefetch step 0's W frags
  {
    const float* p = xb + (size_t)srow * Dd + sd0;
    float4 u0 = *(const float4*)(p + 0), u1 = *(const float4*)(p + 4);
    float4 u2 = *(const float4*)(p + 8), u3 = *(const float4*)(p + 12);
    const float uu[16] = {u0.x,u0.y,u0.z,u0.w, u1.x,u1.y,u1.z,u1.w,
                          u2.x,u2.y,u2.z,u2.w, u3.x,u3.y,u3.z,u3.w};
    #pragma unroll
    for (int j = 0; j < 16; ++j)
      *(unsigned short*)(xs + lds2((unsigned)(sd0 + j), (unsigned)(srow * 2))) = f2bf(uu[j]);
  }
  bf16x8 wf[2][2];   // [ks2][mi] current step's W fragments
  #pragma unroll
  for (int ks2 = 0; ks2 < 2; ++ks2)
    #pragma unroll
    for (int mi = 0; mi < 2; ++mi)
      wf[ks2][mi] = *(const bf16x8*)(Wb + (size_t)(wr * 32 + mi * 16 + ln) * Nn
                                        + ks2 * 32 + g * 8);
  __syncthreads();

  int cur = 0;
  for (int s = 0; s < CH2; ++s) {          // 8 n-steps of 64
    // issue next step's x loads AND W-frag loads before compute
    float4 n0, n1, n2, n3;
    bf16x8 wn[2][2];
    if (s + 1 < CH2) {
      const float* p = xb + (size_t)((s + 1) * NSTEP + srow) * Dd + sd0;
      n0 = *(const float4*)(p + 0); n1 = *(const float4*)(p + 4);
      n2 = *(const float4*)(p + 8); n3 = *(const float4*)(p + 12);
      #pragma unroll
      for (int ks2 = 0; ks2 < 2; ++ks2)
        #pragma unroll
        for (int mi = 0; mi < 2; ++mi)
          wn[ks2][mi] = *(const bf16x8*)(Wb + (size_t)(wr * 32 + mi * 16 + ln) * Nn
                                            + (s + 1) * NSTEP + ks2 * 32 + g * 8);
    }

    const char* xcur = xs + (cur << 15);
    #pragma unroll
    for (int ks2 = 0; ks2 < 2; ++ks2) {
      bf16x8 bg[4];
      #pragma unroll
      for (int ni = 0; ni < 4; ++ni)
        bg[ni] = *(const bf16x8*)(xcur + lds2((unsigned)(wc * 64 + ni * 16 + ln),
                                              (unsigned)((ks2 * 32 + g * 8) * 2)));
      #pragma unroll
      for (int mi = 0; mi < 2; ++mi) {
        float wsp = 0.f;
        #pragma unroll
        for (int j = 0; j < 8; ++j) wsp += bf2f((unsigned short)wf[ks2][mi][j]);
        if (mi == 0) ws0 += wsp; else ws1 += wsp;
        #pragma unroll
        for (int ni = 0; ni < 4; ++ni)
          acc[mi][ni] = __builtin_amdgcn_mfma_f32_16x16x32_bf16(wf[ks2][mi], bg[ni], acc[mi][ni], 0, 0, 0);
      }
    }

    if (s + 1 < CH2) {
      // write-late: LDS writes to the opposite buffer (no reader this step)
      char* xn = xs + ((cur ^ 1) << 15);
      const float uu[16] = {n0.x,n0.y,n0.z,n0.w, n1.x,n1.y,n1.z,n1.w,
                            n2.x,n2.y,n2.z,n2.w, n3.x,n3.y,n3.z,n3.w};
      #pragma unroll
      for (int j = 0; j < 16; ++j)
        *(unsigned short*)(xn + lds2((unsigned)(sd0 + j), (unsigned)(srow * 2))) = f2bf(uu[j]);
      #pragma unroll
      for (int ks2 = 0; ks2 < 2; ++ks2)
        #pragma unroll
        for (int mi = 0; mi < 2; ++mi)
          wf[ks2][mi] = wn[ks2][mi];
    }
    __syncthreads();   // single barrier per step
    cur ^= 1;
  }

  // Wsum_chunk[k]: reduce across g (frags covered disjoint n-slices), publish once
  ws0 += __shfl_xor(ws0, 16); ws0 += __shfl_xor(ws0, 32);
  ws1 += __shfl_xor(ws1, 16); ws1 += __shfl_xor(ws1, 32);
  if (wc == 0 && l < 16) {
    wsL[wr * 32 + l]      = ws0;
    wsL[wr * 32 + 16 + l] = ws1;
  }
  __syncthreads();

  #pragma unroll
  for (int mi = 0; mi < 2; ++mi) {
    #pragma unroll
    for (int r = 0; r < 4; ++r) {
      const int k = wr * 32 + mi * 16 + g * 4 + r;
      const float wsv = wsL[k];
      #pragma unroll
      for (int ni = 0; ni < 4; ++ni) {
        const int d = wc * 64 + ni * 16 + ln;
        const float v = acc[mi][ni][r] - wsv * cwf[k * Dd + d];
        if (PM == 0) {
          Ep[(size_t)blockIdx.x * (Kk * Dd) + k * Dd + d] = v;
        } else {
          atomicAdd(out + (size_t)b * (Kk * Dd) + k * Dd + d, v);
        }
      }
    }
  }
}

// ---------------- k3: out = sum over 8 chunk-partials (16 floats/thread)
__global__ __launch_bounds__(256, 1) void enc_reduce_f32(
    const float* __restrict__ Ep, float* __restrict__ out) {
  const size_t i = ((size_t)blockIdx.x * 256 + threadIdx.x) * 16;
  const int b   = (int)(i / (Kk * Dd));
  const int rem = (int)(i % (Kk * Dd));
  const float* p = Ep + (size_t)b * CH2 * (Kk * Dd) + rem;
  float sx[16];
  #pragma unroll
  for (int j = 0; j < 16; ++j) sx[j] = 0.f;
  #pragma unroll
  for (int c = 0; c < CH2; ++c) {
    const float4* q = (const float4*)(p + (size_t)c * (Kk * Dd));
    float4 v0 = q[0], v1 = q[1], v2 = q[2], v3 = q[3];
    sx[0] += v0.x; sx[1] += v0.y; sx[2]  += v0.z; sx[3]  += v0.w;
    sx[4] += v1.x; sx[5] += v1.y; sx[6]  += v1.z; sx[7]  += v1.w;
    sx[8] += v2.x; sx[9] += v2.y; sx[10] += v2.z; sx[11] += v2.w;
    sx[12] += v3.x; sx[13] += v3.y; sx[14] += v3.z; sx[15] += v3.w;
  }
  float4* o = (float4*)(out + i);
  o[0] = make_float4(sx[0], sx[1], sx[2], sx[3]);
  o[1] = make_float4(sx[4], sx[5], sx[6], sx[7]);
  o[2] = make_float4(sx[8], sx[9], sx[10], sx[11]);
  o[3] = make_float4(sx[12], sx[13], sx[14], sx[15]);
}

extern "C" void kernel_launch(void* const* d_in, const int* in_sizes, int n_in,
                              void* d_out, int out_size, void* d_ws, size_t ws_size,
                              hipStream_t stream) {
  const float* x  = (const float*)d_in[0];   // (32, 4096, 256)
  const float* cw = (const float*)d_in[1];   // (128, 256)
  const float* sc = (const float*)d_in[2];   // (128,)
  float* out = (float*)d_out;                // (32, 128, 256)

  unsigned short* cbf = (unsigned short*)d_ws;                      // 64KB
  float2* tab = (float2*)((char*)d_ws + 65536);                     // 1KB
  unsigned short* Wt = (unsigned short*)((char*)d_ws + 66560);      // 33.55MB W^T bf16
  float* Ep = (float*)((char*)d_ws + 66560 + (size_t)32 * Kk * Nn * 2);  // 33.55MB fp32
  const size_t KD = (size_t)Kk * Dd;
  const size_t needFull = 66560 + (size_t)32 * Kk * Nn * 2 + (size_t)32 * CH2 * KD * 4;
  const size_t needAtm  = 66560 + (size_t)32 * Kk * Nn * 2;

  enc_prep<<<dim3(Kk), dim3(64), 0, stream>>>(cw, sc, cbf, tab);
  enc_w<<<dim3(32 * SEGS), dim3(512), 0, stream>>>(x, cbf, tab, Wt);

  if (ws_size >= needFull) {
    enc_e<0><<<dim3(32 * CH2), dim3(1024), 0, stream>>>(x, Wt, cw, Ep, nullptr);
    enc_reduce_f32<<<dim3(256), dim3(256), 0, stream>>>(Ep, out);
  } else if (ws_size >= needAtm) {
    hipMemsetAsync(d_out, 0, (size_t)out_size * sizeof(float), stream);
    enc_e<2><<<dim3(32 * CH2), dim3(1024), 0, stream>>>(x, Wt, cw, nullptr, out);
  }
}

// Round 14
// 94.559 us; speedup vs baseline: 1.5382x; 1.0505x over previous
//
#include <hip/hip_runtime.h>

#define DEV __device__ __forceinline__

typedef __attribute__((ext_vector_type(8))) short bf16x8;
typedef __attribute__((ext_vector_type(4))) float f32x4;

constexpr int Nn = 4096, Dd = 256, Kk = 128;
constexpr int SEGS = 32;          // k1 segments per batch (128 rows each)
constexpr int CH2  = 8;           // k2 n-chunks per batch (512 rows each)
constexpr int NCH  = Nn / CH2;    // 512 rows per k2 block
constexpr int NSTEP = 64;         // k2 n-step

DEV unsigned short f2bf(float f) {
  unsigned int u = __builtin_bit_cast(unsigned int, f);
  u += 0x7FFFu + ((u >> 16) & 1u);          // RNE; inputs are finite
  return (unsigned short)(u >> 16);
}
DEV float bf2f(unsigned short h) {
  unsigned int u = (unsigned int)h << 16;
  return __builtin_bit_cast(float, u);
}

// k2 xT tile: row d = 128B (64 bf16 n-values). Swizzle 16B slot by
// hh(d) = (d&7)^((d>>4)&7)^(((d>>7)&1)<<1):
//  - staging writes (lane ln scatters d=ln*16+j): <=4-way (writes only)
//  - b128 frag reads (lanes d=base+ln):           <=2-way (free)
DEV unsigned lds2(unsigned d, unsigned nbyte) {
  unsigned hh = (d & 7u) ^ ((d >> 4) & 7u) ^ (((d >> 7) & 1u) << 1);
  return d * 128u + (nbyte ^ (hh << 4));
}

// k1 cbf LDS tile: row k = 512B (256 bf16 d-values). XOR byte bits 4-6 by
// (row&7): the 16-row b128 frag read spreads across the 8 bank-quads.
DEV unsigned ldsc(unsigned row, unsigned byteInRow) {
  return row * 512u + (byteInRow ^ ((row & 7u) << 4));
}

// k1 W-transpose tile: row k = 256B (128 bf16 n-values). h includes k bit3 so
// the 4 lane-groups (k = f*16 + g*4 + r) land on 4 distinct 16B slots ->
// scalar write pass conflict-free; row-contiguous read pass free.
DEV unsigned ldsw(unsigned k, unsigned nbyte) {
  unsigned h = (k & 7u) ^ (((k >> 3) & 1u) << 1);
  return k * 256u + (nbyte ^ (h << 4));
}

__global__ void enc_prep(const float* __restrict__ cw, const float* __restrict__ sc,
                         unsigned short* __restrict__ cbf, float2* __restrict__ tab) {
  int k = blockIdx.x, l = threadIdx.x;          // 128 blocks x 64 threads
  float4 u = *(const float4*)(cw + k * Dd + l * 4);
  float s2 = u.x * u.x + u.y * u.y + u.z * u.z + u.w * u.w;
  #pragma unroll
  for (int o = 1; o < 64; o <<= 1) s2 += __shfl_xor(s2, o);
  unsigned short* dst = cbf + k * Dd + l * 4;
  dst[0] = f2bf(u.x); dst[1] = f2bf(u.y); dst[2] = f2bf(u.z); dst[3] = f2bf(u.w);
  if (l == 0) { float s = sc[k]; tab[k] = make_float2(s * s2, 2.0f * s); }
}

// ---------------- k1: W^T producer. Full-row x prefetch; cbf in swizzled LDS;
// W-tile transposed through LDS so Wt stores are coalesced dwordx4.
__global__ __launch_bounds__(512, 1) void enc_w(
    const float* __restrict__ x, const unsigned short* __restrict__ cbf,
    const float2* __restrict__ tab, unsigned short* __restrict__ Wt) {
  __shared__ __align__(16) char cL[65536];       // cbf tile; reused as W staging
  __shared__ float2 tabL[Kk];
  const int tid = threadIdx.x;
  const int w  = tid >> 6;             // wave 0..7
  const int l  = tid & 63;
  const int g  = l >> 4;               // 16-lane group 0..3
  const int ln = l & 15;

  // stage cbf -> swizzled LDS: thread i copies 128B (row i/4, quarter i%4)
  {
    const int r = tid >> 2, part = tid & 3;
    const char* src = (const char*)cbf + r * 512 + part * 128;
    #pragma unroll
    for (int j = 0; j < 8; ++j) {
      float4 v = *(const float4*)(src + j * 16);
      *(float4*)(cL + ldsc((unsigned)r, (unsigned)(part * 128 + j * 16))) = v;
    }
  }
  if (tid < Kk) tabL[tid] = tab[tid];
  __syncthreads();

  const int b   = blockIdx.x >> 5;     // 32 batches x 32 segments
  const int seg = blockIdx.x & 31;
  const int nrow = seg * 128 + w * 16 + ln;            // row within batch
  const float* xrow = x + ((size_t)b * Nn + nrow) * Dd;

  f32x4 s1[8];
  const f32x4 zero4 = {0.f, 0.f, 0.f, 0.f};
  #pragma unroll
  for (int f = 0; f < 8; ++f) s1[f] = zero4;
  float x2p = 0.f;

  // full-row prefetch: 16 independent loads in flight before any consumption
  float4 pu[8][2];
  #pragma unroll
  for (int p = 0; p < 8; ++p) {
    pu[p][0] = *(const float4*)(xrow + p * 32 + g * 8);
    pu[p][1] = *(const float4*)(xrow + p * 32 + g * 8 + 4);
  }

  #pragma unroll
  for (int ks = 0; ks < 8; ++ks) {
    float4 u0 = pu[ks][0], u1 = pu[ks][1];
    x2p += u0.x*u0.x + u0.y*u0.y + u0.z*u0.z + u0.w*u0.w
         + u1.x*u1.x + u1.y*u1.y + u1.z*u1.z + u1.w*u1.w;
    bf16x8 xv;
    xv[0] = (short)f2bf(u0.x); xv[1] = (short)f2bf(u0.y);
    xv[2] = (short)f2bf(u0.z); xv[3] = (short)f2bf(u0.w);
    xv[4] = (short)f2bf(u1.x); xv[5] = (short)f2bf(u1.y);
    xv[6] = (short)f2bf(u1.z); xv[7] = (short)f2bf(u1.w);
    const unsigned colb = (unsigned)(ks * 64 + g * 16);
    #pragma unroll
    for (int f = 0; f < 8; ++f) {
      bf16x8 a = *(const bf16x8*)(cL + ldsc((unsigned)(f * 16 + ln), colb));
      s1[f] = __builtin_amdgcn_mfma_f32_16x16x32_bf16(a, xv, s1[f], 0, 0, 0);
    }
  }

  x2p += __shfl_xor(x2p, 16); x2p += __shfl_xor(x2p, 32);
  const float hx2 = 0.5f * x2p;
  float ssum = 0.f;
  #pragma unroll
  for (int f = 0; f < 8; ++f) {
    #pragma unroll
    for (int r = 0; r < 4; ++r) {
      const float2 ab = tabL[f * 16 + g * 4 + r];
      const float ev = __expf(ab.x + ab.y * (hx2 - s1[f][r]));
      s1[f][r] = ev;
      ssum += ev;
    }
  }
  ssum += __shfl_xor(ssum, 16); ssum += __shfl_xor(ssum, 32);
  const float rinv = 1.0f / ssum;

  // transpose W through LDS (reuse cL: all cbf reads are done)
  __syncthreads();
  #pragma unroll
  for (int f = 0; f < 8; ++f) {
    #pragma unroll
    for (int r = 0; r < 4; ++r) {
      const int cwi = f * 16 + g * 4 + r;
      *(unsigned short*)(cL + ldsw((unsigned)cwi, (unsigned)((w * 16 + ln) * 2)))
          = f2bf(s1[f][r] * rinv);
    }
  }
  __syncthreads();
  // coalesced store: instr j covers local tile bytes tid*16 + j*8192
  {
    char* wq = (char*)(Wt + (size_t)b * Kk * Nn + seg * 128);
    #pragma unroll
    for (int j = 0; j < 4; ++j) {
      const unsigned o = (unsigned)tid * 16u + (unsigned)j * 8192u;
      const unsigned k = o >> 8, nb = o & 255u;
      float4 v = *(const float4*)(cL + ldsw(k, nb));
      *(float4*)(wq + (size_t)k * (Nn * 2) + nb) = v;
    }
  }
}

// ---------------- k2: Ep_chunk[k][d] = sum_n W^T[k][n] x[n][d] - Wsum_chunk[k] c[k][d]
// Double-buffered LDS xT, issue-early/write-late staging, W frags prefetched one
// step ahead in registers, one barrier per step. PM: 0 = bf16 partials, 2 = atomic.
template<int PM>
__global__ __launch_bounds__(1024) void enc_e(
    const float* __restrict__ x, const unsigned short* __restrict__ Wt,
    const float* __restrict__ cwf, unsigned short* __restrict__ Ep,
    float* __restrict__ out) {
  __shared__ __align__(16) char xs[2 * 32768];   // xT [256 d][64 n] bf16, dbuf
  __shared__ float wsL[Kk];

  const int tid = threadIdx.x;
  const int w  = tid >> 6;             // wave 0..15
  const int l  = tid & 63;
  const int g  = l >> 4;
  const int ln = l & 15;
  const int wr = w >> 2, wc = w & 3;   // 4x4 wave grid over E(128k x 256d)
  const int b  = blockIdx.x >> 3, ch = blockIdx.x & 7;

  const float* xb = x + ((size_t)b * Nn + ch * NCH) * Dd;
  const unsigned short* Wb = Wt + (size_t)b * Kk * Nn + ch * NCH;

  // staging role: row n_loc = w*4+g (0..63), d-slice = ln*16..+15 (16 floats)
  const int srow = w * 4 + g;
  const int sd0  = ln * 16;

  f32x4 acc[2][4];
  const f32x4 zero4 = {0.f, 0.f, 0.f, 0.f};
  #pragma unroll
  for (int mi = 0; mi < 2; ++mi)
    #pragma unroll
    for (int ni = 0; ni < 4; ++ni) acc[mi][ni] = zero4;
  float ws0 = 0.f, ws1 = 0.f;

  // prologue: stage step 0 into buf 0; prefetch step 0's W frags
  {
    const float* p = xb + (size_t)srow * Dd + sd0;
    float4 u0 = *(const float4*)(p + 0), u1 = *(const float4*)(p + 4);
    float4 u2 = *(const float4*)(p + 8), u3 = *(const float4*)(p + 12);
    const float uu[16] = {u0.x,u0.y,u0.z,u0.w, u1.x,u1.y,u1.z,u1.w,
                          u2.x,u2.y,u2.z,u2.w, u3.x,u3.y,u3.z,u3.w};
    #pragma unroll
    for (int j = 0; j < 16; ++j)
      *(unsigned short*)(xs + lds2((unsigned)(sd0 + j), (unsigned)(srow * 2))) = f2bf(uu[j]);
  }
  bf16x8 wf[2][2];   // [ks2][mi] current step's W fragments
  #pragma unroll
  for (int ks2 = 0; ks2 < 2; ++ks2)
    #pragma unroll
    for (int mi = 0; mi < 2; ++mi)
      wf[ks2][mi] = *(const bf16x8*)(Wb + (size_t)(wr * 32 + mi * 16 + ln) * Nn
                                        + ks2 * 32 + g * 8);
  __syncthreads();

  int cur = 0;
  for (int s = 0; s < CH2; ++s) {          // 8 n-steps of 64
    // issue next step's x loads AND W-frag loads before compute
    float4 n0, n1, n2, n3;
    bf16x8 wn[2][2];
    if (s + 1 < CH2) {
      const float* p = xb + (size_t)((s + 1) * NSTEP + srow) * Dd + sd0;
      n0 = *(const float4*)(p + 0); n1 = *(const float4*)(p + 4);
      n2 = *(const float4*)(p + 8); n3 = *(const float4*)(p + 12);
      #pragma unroll
      for (int ks2 = 0; ks2 < 2; ++ks2)
        #pragma unroll
        for (int mi = 0; mi < 2; ++mi)
          wn[ks2][mi] = *(const bf16x8*)(Wb + (size_t)(wr * 32 + mi * 16 + ln) * Nn
                                            + (s + 1) * NSTEP + ks2 * 32 + g * 8);
    }

    const char* xcur = xs + (cur << 15);
    #pragma unroll
    for (int ks2 = 0; ks2 < 2; ++ks2) {
      bf16x8 bg[4];
      #pragma unroll
      for (int ni = 0; ni < 4; ++ni)
        bg[ni] = *(const bf16x8*)(xcur + lds2((unsigned)(wc * 64 + ni * 16 + ln),
                                              (unsigned)((ks2 * 32 + g * 8) * 2)));
      #pragma unroll
      for (int mi = 0; mi < 2; ++mi) {
        float wsp = 0.f;
        #pragma unroll
        for (int j = 0; j < 8; ++j) wsp += bf2f((unsigned short)wf[ks2][mi][j]);
        if (mi == 0) ws0 += wsp; else ws1 += wsp;
        #pragma unroll
        for (int ni = 0; ni < 4; ++ni)
          acc[mi][ni] = __builtin_amdgcn_mfma_f32_16x16x32_bf16(wf[ks2][mi], bg[ni], acc[mi][ni], 0, 0, 0);
      }
    }

    if (s + 1 < CH2) {
      // write-late: LDS writes to the opposite buffer (no reader this step)
      char* xn = xs + ((cur ^ 1) << 15);
      const float uu[16] = {n0.x,n0.y,n0.z,n0.w, n1.x,n1.y,n1.z,n1.w,
                            n2.x,n2.y,n2.z,n2.w, n3.x,n3.y,n3.z,n3.w};
      #pragma unroll
      for (int j = 0; j < 16; ++j)
        *(unsigned short*)(xn + lds2((unsigned)(sd0 + j), (unsigned)(srow * 2))) = f2bf(uu[j]);
      #pragma unroll
      for (int ks2 = 0; ks2 < 2; ++ks2)
        #pragma unroll
        for (int mi = 0; mi < 2; ++mi)
          wf[ks2][mi] = wn[ks2][mi];
    }
    __syncthreads();   // single barrier per step
    cur ^= 1;
  }

  // Wsum_chunk[k]: reduce across g (frags covered disjoint n-slices), publish once
  ws0 += __shfl_xor(ws0, 16); ws0 += __shfl_xor(ws0, 32);
  ws1 += __shfl_xor(ws1, 16); ws1 += __shfl_xor(ws1, 32);
  if (wc == 0 && l < 16) {
    wsL[wr * 32 + l]      = ws0;
    wsL[wr * 32 + 16 + l] = ws1;
  }
  __syncthreads();

  #pragma unroll
  for (int mi = 0; mi < 2; ++mi) {
    #pragma unroll
    for (int r = 0; r < 4; ++r) {
      const int k = wr * 32 + mi * 16 + g * 4 + r;
      const float wsv = wsL[k];
      #pragma unroll
      for (int ni = 0; ni < 4; ++ni) {
        const int d = wc * 64 + ni * 16 + ln;
        const float v = acc[mi][ni][r] - wsv * cwf[k * Dd + d];
        if (PM == 0) {
          Ep[(size_t)blockIdx.x * (Kk * Dd) + k * Dd + d] = f2bf(v);
        } else {
          atomicAdd(out + (size_t)b * (Kk * Dd) + k * Dd + d, v);
        }
      }
    }
  }
}

// ---------------- k3: out = sum over 8 bf16 chunk-partials (16 floats/thread)
__global__ __launch_bounds__(256, 1) void enc_reduce_b16(
    const unsigned short* __restrict__ Ep, float* __restrict__ out) {
  const size_t i = ((size_t)blockIdx.x * 256 + threadIdx.x) * 16;
  const int b   = (int)(i / (Kk * Dd));
  const int rem = (int)(i % (Kk * Dd));
  const unsigned short* p = Ep + (size_t)b * CH2 * (Kk * Dd) + rem;
  float sx[16];
  #pragma unroll
  for (int j = 0; j < 16; ++j) sx[j] = 0.f;
  #pragma unroll
  for (int c = 0; c < CH2; ++c) {
    const ushort4* q = (const ushort4*)(p + (size_t)c * (Kk * Dd));
    ushort4 v0 = q[0], v1 = q[1], v2 = q[2], v3 = q[3];
    sx[0]  += bf2f(v0.x); sx[1]  += bf2f(v0.y); sx[2]  += bf2f(v0.z); sx[3]  += bf2f(v0.w);
    sx[4]  += bf2f(v1.x); sx[5]  += bf2f(v1.y); sx[6]  += bf2f(v1.z); sx[7]  += bf2f(v1.w);
    sx[8]  += bf2f(v2.x); sx[9]  += bf2f(v2.y); sx[10] += bf2f(v2.z); sx[11] += bf2f(v2.w);
    sx[12] += bf2f(v3.x); sx[13] += bf2f(v3.y); sx[14] += bf2f(v3.z); sx[15] += bf2f(v3.w);
  }
  float4* o = (float4*)(out + i);
  o[0] = make_float4(sx[0], sx[1], sx[2], sx[3]);
  o[1] = make_float4(sx[4], sx[5], sx[6], sx[7]);
  o[2] = make_float4(sx[8], sx[9], sx[10], sx[11]);
  o[3] = make_float4(sx[12], sx[13], sx[14], sx[15]);
}

extern "C" void kernel_launch(void* const* d_in, const int* in_sizes, int n_in,
                              void* d_out, int out_size, void* d_ws, size_t ws_size,
                              hipStream_t stream) {
  const float* x  = (const float*)d_in[0];   // (32, 4096, 256)
  const float* cw = (const float*)d_in[1];   // (128, 256)
  const float* sc = (const float*)d_in[2];   // (128,)
  float* out = (float*)d_out;                // (32, 128, 256)

  unsigned short* cbf = (unsigned short*)d_ws;                      // 64KB
  float2* tab = (float2*)((char*)d_ws + 65536);                     // 1KB
  unsigned short* Wt = (unsigned short*)((char*)d_ws + 66560);      // 33.55MB W^T bf16
  unsigned short* Ep = (unsigned short*)((char*)d_ws + 66560 + (size_t)32 * Kk * Nn * 2); // 16.8MB bf16
  const size_t KD = (size_t)Kk * Dd;
  const size_t needFull = 66560 + (size_t)32 * Kk * Nn * 2 + (size_t)32 * CH2 * KD * 2;
  const size_t needAtm  = 66560 + (size_t)32 * Kk * Nn * 2;

  enc_prep<<<dim3(Kk), dim3(64), 0, stream>>>(cw, sc, cbf, tab);
  enc_w<<<dim3(32 * SEGS), dim3(512), 0, stream>>>(x, cbf, tab, Wt);

  if (ws_size >= needFull) {
    enc_e<0><<<dim3(32 * CH2), dim3(1024), 0, stream>>>(x, Wt, cw, Ep, nullptr);
    enc_reduce_b16<<<dim3(256), dim3(256), 0, stream>>>(Ep, out);
  } else if (ws_size >= needAtm) {
    hipMemsetAsync(d_out, 0, (size_t)out_size * sizeof(float), stream);
    enc_e<2><<<dim3(32 * CH2), dim3(1024), 0, stream>>>(x, Wt, cw, nullptr, out);
  }
}